// Round 13
// baseline (164.820 us; speedup 1.0000x reference)
//
#include <hip/hip_runtime.h>

#define N 8192
#define D 128
#define CHUNK 512
#define NCC (N / CHUNK)        // 16 column chunks
#define TILE_IT (CHUNK / 128)  // 4 B-tiles per chunk
#define NBIN 81                // labels -1..79 -> bins 0..80
#define NBLK 512               // grid: (32,16) = 512 blocks = exactly 2/CU
#define MAGIC 0x7A3B9C1Du      // non-repeating bytes: no fill pattern matches

typedef unsigned short u16;
typedef __attribute__((ext_vector_type(8))) __bf16 bf16x8;
typedef __attribute__((ext_vector_type(4))) float f32x4;

// scale = sqrt(10 * log2(e)): dot of two scaled rows = log2(e^{cos/T}),
// so e^{sim} = exp2(acc) with NO per-element multiply.
#define PREP_SCALE 3.7982889979f

__device__ __forceinline__ u16 f2bf(float x) {
  unsigned u = __float_as_uint(x);
  u += 0x7fff + ((u >> 16) & 1);  // RNE
  return (u16)(u >> 16);
}

struct SMemA {  // phase A: counting-sort workspace (~5.5 KB)
  int hist[4][NBIN], part[4][NBIN], lbase[NBIN], lpos[16];
};
struct SMemB {  // phase B/C: B-tiles + labels + reduce (~66 KB)
  u16 Bh[2][128 * 128];
  int Lab[CHUNK];
  float red[3][4];
};
union SMem { SMemA a; SMemB b; };  // phases are barrier-separated

// ============================================================================
// ONE dispatch. 512 blocks, 67.6 KB LDS -> exactly 2/CU on 256 CUs: all
// blocks provably co-resident, so a manual spin barrier cannot deadlock
// (cooperative launch itself fails under graph capture — R2).
//   init: first-arriving block (atomicExch election) zeroes ctr1/ctr2/acc3,
//         then release-stores MAGIC flag. Poison-safe; per-iteration
//         re-poison (the 42us fill) resets the election each replay.
//   A: R6-proven parallel counting-sort rank + normalize (16 rows/block).
//   barrier1 (fence + u32 ctr + spin w/ s_sleep; acquire fence after).
//   B: R9-proven fused sim loop, verbatim (2-phase LDS staging, sorted-label
//      fast path, loss = log(as/ps) — clips provably inactive, absmax 0.0
//      across R4-R12).
//   barrier2: all blocks release (fence + add); only blocks 0..31 spin.
//   C: R0-proven rows reduction with CACHED loads (acquire fence makes them
//      coherent — fixes R5's uncached-read mistake) + acc3/out finalize.
// Saves 2 dispatch gaps (~10 us) vs the 3-kernel chain.
// ============================================================================
__global__ __launch_bounds__(256, 2) void cpe_fused(
    const float* __restrict__ feat, const int* __restrict__ labels,
    u16* __restrict__ fhi, int* __restrict__ slab,
    float2* __restrict__ partials, unsigned* __restrict__ ctl,
    float* __restrict__ acc3, float* __restrict__ out) {
  __shared__ SMem sm;
  const int tid = threadIdx.x;
  const int w = tid >> 6, l = tid & 63, q = l >> 4, m = l & 15;
  const int rt = blockIdx.x, cc = blockIdx.y;  // grid (32,16)
  const int bid = cc * 32 + rt;                // 0..511

  // ---- barrier-state init election (first block to arrive wins) ----------
  if (tid == 0) {
    if (atomicExch(&ctl[0], MAGIC) != MAGIC) {
      __hip_atomic_store(&ctl[2], 0u, __ATOMIC_RELAXED, __HIP_MEMORY_SCOPE_AGENT);
      __hip_atomic_store(&ctl[3], 0u, __ATOMIC_RELAXED, __HIP_MEMORY_SCOPE_AGENT);
#pragma unroll
      for (int k = 0; k < 4; ++k)
        __hip_atomic_store(&acc3[k], 0.0f, __ATOMIC_RELAXED, __HIP_MEMORY_SCOPE_AGENT);
      __threadfence();  // release init
      __hip_atomic_store(&ctl[1], MAGIC, __ATOMIC_RELAXED, __HIP_MEMORY_SCOPE_AGENT);
    }
  }

  // ================= phase A: sort rank + normalize 16 rows =================
  if (tid < NBIN) {
#pragma unroll
    for (int cp = 0; cp < 4; ++cp) { sm.a.hist[cp][tid] = 0; sm.a.part[cp][tid] = 0; }
  }
  __syncthreads();
  const int myBase = bid * 16;  // this block's 16 ORIGINAL rows
  for (int j = tid; j < N; j += 256) {
    const int lab = labels[j] + 1;  // 0..80
    atomicAdd(&sm.a.hist[w][lab], 1);
    if (j < myBase) atomicAdd(&sm.a.part[w][lab], 1);
  }
  __syncthreads();
  if (tid < NBIN) {
    sm.a.hist[0][tid] += sm.a.hist[1][tid] + sm.a.hist[2][tid] + sm.a.hist[3][tid];
    sm.a.part[0][tid] += sm.a.part[1][tid] + sm.a.part[2][tid] + sm.a.part[3][tid];
  }
  __syncthreads();
  if (tid == 0) {  // exclusive scan of 81 bins — trivial
    int s = 0;
    for (int b = 0; b < NBIN; ++b) { sm.a.lbase[b] = s; s += sm.a.hist[0][b]; }
  }
  __syncthreads();
  if (tid < 16) {  // stable rank -> unique sorted position per row
    const int L = labels[myBase + tid] + 1;
    int pos = sm.a.lbase[L] + sm.a.part[0][L];
    for (int k = 0; k < tid; ++k) pos += (labels[myBase + k] + 1 == L) ? 1 : 0;
    sm.a.lpos[tid] = pos;
    slab[pos] = L - 1;
  }
  __syncthreads();
#pragma unroll
  for (int rr = 0; rr < 4; ++rr) {  // one wave per row, 4 rows per wave
    const int k = w * 4 + rr;
    const float2 x = *(const float2*)&feat[(myBase + k) * D + l * 2];
    float s = x.x * x.x + x.y * x.y;
#pragma unroll
    for (int sh = 1; sh < 64; sh <<= 1) s += __shfl_xor(s, sh);
    const float inv = PREP_SCALE / fmaxf(sqrtf(s), 1e-12f);
    const int pos = sm.a.lpos[k];
    *(ushort2*)&fhi[pos * D + l * 2] = make_ushort2(f2bf(x.x * inv), f2bf(x.y * inv));
  }

  // ================= grid barrier 1 (fhi/slab all written) ==================
  __syncthreads();  // all waves' phase-A stores drained to L2 (vmcnt0)
  if (tid == 0) {
    while (__hip_atomic_load(&ctl[1], __ATOMIC_RELAXED, __HIP_MEMORY_SCOPE_AGENT) != MAGIC)
      __builtin_amdgcn_s_sleep(2);
    __threadfence();  // release: flush this XCD's L2 (our fhi/slab rows)
    atomicAdd(&ctl[2], 1u);
    while (__hip_atomic_load(&ctl[2], __ATOMIC_RELAXED, __HIP_MEMORY_SCOPE_AGENT) < NBLK)
      __builtin_amdgcn_s_sleep(2);
    __threadfence();  // acquire: invalidate stale lines before reading fhi
  }
  __syncthreads();

  // ================= phase B: fused sim (R9-proven, verbatim) ===============
  const int r0w = rt * 256 + w * 64;
  const int cbase0 = cc * CHUNK;

#define STAGE(buf, itv)                                                        \
  do {                                                                         \
    const int cbase_ = cbase0 + (itv) * 128;                                   \
    _Pragma("unroll") for (int n = 0; n < 8; ++n) {                            \
      const int r_ = w * 32 + n * 4 + q;                                       \
      const int c_ = m ^ (r_ & 15);                                            \
      const u16* gh_ = &fhi[(size_t)(cbase_ + r_) * D + c_ * 8];               \
      __builtin_amdgcn_global_load_lds(                                        \
          (const __attribute__((address_space(1))) unsigned*)gh_,              \
          (__attribute__((address_space(3))) unsigned*)&sm.b.Bh[buf][(w * 512 + n * 64) * 8], \
          16, 0, 0);                                                           \
    }                                                                          \
  } while (0)

  STAGE(0, 0);  // tile 0 in flight while Lab/A-frags load

  sm.b.Lab[tid] = slab[cbase0 + tid];
  sm.b.Lab[tid + 256] = slab[cbase0 + 256 + tid];

  const int labi_lo = slab[r0w], labi_hi = slab[r0w + 63];

  bf16x8 Ah[4][4];
  int labi[4][4];
#pragma unroll
  for (int tr = 0; tr < 4; ++tr) {
    const int row = r0w + tr * 16 + m;
#pragma unroll
    for (int ks = 0; ks < 4; ++ks)
      Ah[tr][ks] = *(const bf16x8*)&fhi[row * D + ks * 32 + q * 8];
#pragma unroll
    for (int v = 0; v < 4; ++v) labi[tr][v] = slab[r0w + tr * 16 + q * 4 + v];
  }

  float ps[4][4], as_[4][4];
#pragma unroll
  for (int tr = 0; tr < 4; ++tr)
#pragma unroll
    for (int v = 0; v < 4; ++v) { ps[tr][v] = 0.f; as_[tr][v] = 0.f; }

  __syncthreads();  // Lab ready + tile 0 staged (vmcnt drained)

  for (int it = 0; it < TILE_IT; ++it) {
    const int cur = it & 1;
    if (it + 1 < TILE_IT) STAGE(cur ^ 1, it + 1);  // overlap: next tile DMA
    const int cbase = cbase0 + it * 128;

    for (int ct = 0; ct < 8; ++ct) {
      const int tb = it * 128 + ct * 16;
      const int labj_lo = sm.b.Lab[tb], labj_hi = sm.b.Lab[tb + 15];
      if (labj_hi < 0) continue;  // all-bg tile: every em==0, skip MFMA too
      const bool slow = (labj_lo < 0) | ((labj_hi >= labi_lo) & (labj_lo <= labi_hi));
      const int jj = ct * 16 + m;
      f32x4 acc[4];
#pragma unroll
      for (int tr = 0; tr < 4; ++tr) acc[tr] = (f32x4){0.f, 0.f, 0.f, 0.f};
#pragma unroll
      for (int ks = 0; ks < 4; ++ks) {
        const int off = jj * 128 + ((ks * 4 + q) ^ m) * 8;  // swizzled chunk
        const bf16x8 bh = *(const bf16x8*)&sm.b.Bh[cur][off];
#pragma unroll
        for (int tr = 0; tr < 4; ++tr)
          acc[tr] = __builtin_amdgcn_mfma_f32_16x16x32_bf16(Ah[tr][ks], bh, acc[tr], 0, 0, 0);
      }
      if (!slow) {
        // fast path (~97% of tiles): all-fg, no positives, no self
#pragma unroll
        for (int tr = 0; tr < 4; ++tr)
#pragma unroll
          for (int v = 0; v < 4; ++v)
            as_[tr][v] += __builtin_amdgcn_exp2f(acc[tr][v]);
      } else {
        const int labj = sm.b.Lab[tb + m];
        const bool fgj = labj >= 0;
        const int jbase = cbase + ct * 16;
#pragma unroll
        for (int tr = 0; tr < 4; ++tr) {
          if (jbase == r0w + tr * 16) {  // wave-uniform diagonal-tile branch
#pragma unroll
            for (int v = 0; v < 4; ++v) {
              const float e = __builtin_amdgcn_exp2f(acc[tr][v]);
              const float em = (fgj && (m != q * 4 + v)) ? e : 0.0f;
              as_[tr][v] += em;
              ps[tr][v] += (labj == labi[tr][v]) ? em : 0.0f;
            }
          } else {
#pragma unroll
            for (int v = 0; v < 4; ++v) {
              const float e = __builtin_amdgcn_exp2f(acc[tr][v]);
              const float em = fgj ? e : 0.0f;
              as_[tr][v] += em;
              ps[tr][v] += (labj == labi[tr][v]) ? em : 0.0f;
            }
          }
        }
      }
    }
    __syncthreads();  // Bh[cur] consumed; next tile staged (vmcnt drained)
  }
#undef STAGE

  // row partials: reduce over the 16 m-lanes; plain float2 store per row
#pragma unroll
  for (int tr = 0; tr < 4; ++tr)
#pragma unroll
    for (int v = 0; v < 4; ++v) {
      float vp = ps[tr][v], va = as_[tr][v];
#pragma unroll
      for (int s = 1; s < 16; s <<= 1) {
        vp += __shfl_xor(vp, s);
        va += __shfl_xor(va, s);
      }
      if (m == 0)
        partials[(size_t)cc * N + r0w + tr * 16 + q * 4 + v] = make_float2(vp, va);
    }

  // ================= grid barrier 2 (release-only for most) =================
  __syncthreads();  // partial stores drained (vmcnt0)
  if (tid == 0) {
    __threadfence();       // release partials
    atomicAdd(&ctl[3], 1u);
  }
  if (bid >= 32) return;   // 480 blocks exit; CUs free up immediately

  if (tid == 0) {
    while (__hip_atomic_load(&ctl[3], __ATOMIC_RELAXED, __HIP_MEMORY_SCOPE_AGENT) < NBLK)
      __builtin_amdgcn_s_sleep(2);
    __threadfence();       // acquire: partials now coherent for cached loads
  }
  __syncthreads();

  // ================= phase C: per-row loss -> mean (32 blocks) ==============
  const int r = bid * 256 + tid;
  float psr = 0.f, asr = 0.f;
#pragma unroll
  for (int c = 0; c < NCC; ++c) {
    const float2 p = partials[(size_t)c * N + r];  // cached (post-acquire)
    psr += p.x;
    asr += p.y;
  }
  const bool fg = slab[r] >= 0;
  const bool valid = fg && (psr > 0.f);  // e>0 => (npos>0 <=> ps>0)
  const float loss = fminf(logf(asr / psr), 10.0f);
  float v0 = valid ? loss : 0.f;
  float v1 = valid ? 1.f : 0.f;
  float v2 = fg ? 1.f : 0.f;
#pragma unroll
  for (int s = 1; s < 64; s <<= 1) {
    v0 += __shfl_xor(v0, s);
    v1 += __shfl_xor(v1, s);
    v2 += __shfl_xor(v2, s);
  }
  if (l == 0) { sm.b.red[0][w] = v0; sm.b.red[1][w] = v1; sm.b.red[2][w] = v2; }
  __syncthreads();
  if (tid == 0) {
    atomicAdd(&acc3[0], sm.b.red[0][0] + sm.b.red[0][1] + sm.b.red[0][2] + sm.b.red[0][3]);
    atomicAdd(&acc3[1], sm.b.red[1][0] + sm.b.red[1][1] + sm.b.red[1][2] + sm.b.red[1][3]);
    atomicAdd(&acc3[2], sm.b.red[2][0] + sm.b.red[2][1] + sm.b.red[2][2] + sm.b.red[2][3]);
    __threadfence();
    const unsigned old = atomicAdd((unsigned*)&acc3[3], 1u);
    if (old == 31u) {  // very last finalizer writes out (device-scope reads)
      const float ls = atomicAdd(&acc3[0], 0.0f);
      const float nv = atomicAdd(&acc3[1], 0.0f);
      const float nf = atomicAdd(&acc3[2], 0.0f);
      out[0] = (nf >= 2.0f && nv > 0.0f) ? ls / fmaxf(nv, 1.0f) : 0.0f;
    }
  }
}

extern "C" void kernel_launch(void* const* d_in, const int* in_sizes, int n_in,
                              void* d_out, int out_size, void* d_ws, size_t ws_size,
                              hipStream_t stream) {
  const float* feat = (const float*)d_in[0];
  const int* labels = (const int*)d_in[1];
  float* out = (float*)d_out;
  char* ws = (char*)d_ws;
  u16* fhi = (u16*)ws;                                    // 2 MB
  float2* partials = (float2*)(ws + (size_t)N * D * 2);   // 1 MB (16 chunks)
  char* tail = ws + (size_t)N * D * 2 + (size_t)NCC * N * 8;
  int* slab = (int*)tail;                                 // 32 KB
  float* acc3 = (float*)(tail + N * 4);                   // 4 f32
  unsigned* ctl = (unsigned*)(tail + N * 4 + 64);         // election+flag+2 ctrs

  cpe_fused<<<dim3(32, NCC), 256, 0, stream>>>(feat, labels, fhi, slab,
                                               partials, ctl, acc3, out);
}

// Round 14
// 109.237 us; speedup vs baseline: 1.5088x; 1.5088x over previous
//
#include <hip/hip_runtime.h>

#define N 8192
#define D 128
#define CHUNK 512
#define NCC (N / CHUNK)        // 16 column chunks
#define TILE_IT (CHUNK / 128)  // 4 B-tiles per chunk
#define RROWS 512              // rows per main block (8 waves)
#define NBIN 81                // labels -1..79 -> bins 0..80
#define PBLK 64                // prep grid (128 rows/block)

typedef unsigned short u16;
typedef __attribute__((ext_vector_type(8))) __bf16 bf16x8;
typedef __attribute__((ext_vector_type(4))) float f32x4;

// scale = sqrt(10 * log2(e)): dot of two scaled rows = log2(e^{cos/T}),
// so e^{sim} = exp2(acc) with NO per-element multiply.
#define PREP_SCALE 3.7982889979f

__device__ __forceinline__ u16 f2bf(float x) {
  unsigned u = __float_as_uint(x);
  u += 0x7fff + ((u >> 16) & 1);  // RNE
  return (u16)(u >> 16);
}

// ---- kernel 1: parallel counting-sort rank + normalize + bf16 write --------
// 64 blocks x 128 rows (was 512 x 16): each block still histograms ALL
// labels, so device-wide histogram redundancy drops 8x; normalize total is
// unchanged. Labels staged to LDS for the stable-rank loop. No cross-block
// state. Single-bf16 (absmax 0.0 across R4-R13). Block 0 re-zeroes acc3.
__global__ __launch_bounds__(256) void cpe_prep(const float* __restrict__ feat,
                                                const int* __restrict__ labels,
                                                u16* __restrict__ fhi,
                                                int* __restrict__ slab,
                                                float* __restrict__ acc3) {
  __shared__ int hist[4][NBIN], part[4][NBIN], lbase[NBIN];
  __shared__ int locLab[128], lpos[128];
  const int tid = threadIdx.x;
  const int w = tid >> 6, l = tid & 63;
  const int bid = blockIdx.x;
  const int myBase = bid * 128;  // this block's 128 ORIGINAL rows
  if (tid < NBIN) {
#pragma unroll
    for (int cp = 0; cp < 4; ++cp) { hist[cp][tid] = 0; part[cp][tid] = 0; }
  }
  if (tid < 128) locLab[tid] = labels[myBase + tid] + 1;  // 0..80
  if (bid == 0 && tid >= 128 && tid < 132) acc3[tid - 128] = 0.0f;
  __syncthreads();
  for (int j = tid; j < N; j += 256) {
    const int lab = labels[j] + 1;  // 0..80
    atomicAdd(&hist[w][lab], 1);
    if (j < myBase) atomicAdd(&part[w][lab], 1);
  }
  __syncthreads();
  if (tid < NBIN) {
    hist[0][tid] += hist[1][tid] + hist[2][tid] + hist[3][tid];
    part[0][tid] += part[1][tid] + part[2][tid] + part[3][tid];
  }
  __syncthreads();
  if (tid == 0) {  // exclusive scan of 81 bins — trivial
    int s = 0;
    for (int b = 0; b < NBIN; ++b) { lbase[b] = s; s += hist[0][b]; }
  }
  __syncthreads();
  if (tid < 128) {  // stable rank -> unique sorted position per row
    const int L = locLab[tid];
    int pos = lbase[L] + part[0][L];
    for (int k = 0; k < tid; ++k) pos += (locLab[k] == L) ? 1 : 0;
    lpos[tid] = pos;
    slab[pos] = L - 1;
  }
  __syncthreads();
#pragma unroll 4
  for (int rr = 0; rr < 32; ++rr) {  // one wave per row, 32 rows per wave
    const int k = w * 32 + rr;
    const float2 x = *(const float2*)&feat[(myBase + k) * D + l * 2];
    float s = x.x * x.x + x.y * x.y;
#pragma unroll
    for (int sh = 1; sh < 64; sh <<= 1) s += __shfl_xor(s, sh);
    const float inv = PREP_SCALE / fmaxf(sqrtf(s), 1e-12f);
    const int pos = lpos[k];
    *(ushort2*)&fhi[pos * D + l * 2] = make_ushort2(f2bf(x.x * inv), f2bf(x.y * inv));
  }
}

// ---- kernel 2: fused sim + masked reductions (R12-proven, best: 102.16) ----
// 512-row blocks (512 thr, 8 waves), counted-vmcnt 2-phase staging, sorted-
// label fast path, loss = log(as/ps) (clips provably inactive). One change:
// waves whose 64 rows are ALL background (labi_hi < 0 — sorted prefix) skip
// the compute loop entirely (barriers stay block-uniform, outside ct loop).
__global__ __launch_bounds__(512) void cpe_main(
    const u16* __restrict__ fhi, const int* __restrict__ slab,
    float2* __restrict__ partials) {
  __shared__ __align__(16) u16 Bh[2][128 * 128];  // 2 x 32 KB, XOR-swizzled
  __shared__ int Lab[CHUNK];                      // 2 KB
  const int rt = blockIdx.x, cc = blockIdx.y;     // grid (16,16)
  const int tid = threadIdx.x;
  const int w = tid >> 6, l = tid & 63, q = l >> 4, m = l & 15;
  const int r0w = rt * RROWS + w * 64;
  const int cbase0 = cc * CHUNK;

  // stage a 128-col tile (32 KB): 512 thr x 16B x 4 rounds. LDS slot
  // p = w*256 + n*64 + lane -> (r = p>>4, c' = p&15 = m); c = c' ^ (r&15).
#define STAGE(buf, itv)                                                        \
  do {                                                                         \
    const int cbase_ = cbase0 + (itv) * 128;                                   \
    _Pragma("unroll") for (int n = 0; n < 4; ++n) {                            \
      const int r_ = w * 16 + n * 4 + q;                                       \
      const int c_ = m ^ (r_ & 15);                                            \
      const u16* gh_ = &fhi[(size_t)(cbase_ + r_) * D + c_ * 8];               \
      __builtin_amdgcn_global_load_lds(                                        \
          (const __attribute__((address_space(1))) unsigned*)gh_,              \
          (__attribute__((address_space(3))) unsigned*)&Bh[buf][(w * 256 + n * 64) * 8], \
          16, 0, 0);                                                           \
    }                                                                          \
  } while (0)

  Lab[tid] = slab[cbase0 + tid];  // 512 threads cover CHUNK=512

  // wave-uniform row-label range (labels sorted ascending)
  const int labi_lo = slab[r0w], labi_hi = slab[r0w + 63];
  const bool rowActive = labi_hi >= 0;  // all-bg row wave -> zero partials

  // A fragments + row labels straight from global (L2-resident, once).
  // Issued BEFORE the stages so compiler A-waits never drain stage loads.
  bf16x8 Ah[4][4];
  int labi[4][4];
#pragma unroll
  for (int tr = 0; tr < 4; ++tr) {
    const int row = r0w + tr * 16 + m;
#pragma unroll
    for (int ks = 0; ks < 4; ++ks)
      Ah[tr][ks] = *(const bf16x8*)&fhi[row * D + ks * 32 + q * 8];
#pragma unroll
    for (int v = 0; v < 4; ++v) labi[tr][v] = slab[r0w + tr * 16 + q * 4 + v];
  }

  float ps[4][4], as_[4][4];
#pragma unroll
  for (int tr = 0; tr < 4; ++tr)
#pragma unroll
    for (int v = 0; v < 4; ++v) { ps[tr][v] = 0.f; as_[tr][v] = 0.f; }

  __builtin_amdgcn_sched_barrier(0);  // pin: A/Lab loads above, stages below
  STAGE(0, 0);                        // tile 0 in flight (NOT drained)

  // Lab ds_writes visible to all waves; stages stay outstanding (no vmcnt).
  asm volatile("s_waitcnt lgkmcnt(0)" ::: "memory");
  __builtin_amdgcn_s_barrier();
  __builtin_amdgcn_sched_barrier(0);

#pragma unroll
  for (int it = 0; it < TILE_IT; ++it) {
    const int cur = it & 1;
    if (it > 0) {
      // (A) all waves done reading Bh[cur] from iteration it-1's sibling —
      // safe to overwrite it with tile it+1. No vmcnt drain here.
      asm volatile("s_waitcnt lgkmcnt(0)" ::: "memory");
      __builtin_amdgcn_s_barrier();
      __builtin_amdgcn_sched_barrier(0);
    }
    if (it + 1 < TILE_IT) STAGE(cur ^ 1, it + 1);
    // (B) tile `cur` landed: counted wait leaves the 4 just-issued next-tile
    // loads in flight (T4 — never drain to 0 mid-loop).
    if (it + 1 < TILE_IT)
      asm volatile("s_waitcnt vmcnt(4)" ::: "memory");
    else
      asm volatile("s_waitcnt vmcnt(0)" ::: "memory");
    __builtin_amdgcn_s_barrier();
    __builtin_amdgcn_sched_barrier(0);

    const int cbase = cbase0 + it * 128;
    if (rowActive) {
      for (int ct = 0; ct < 8; ++ct) {
        const int tb = it * 128 + ct * 16;
        const int labj_lo = Lab[tb], labj_hi = Lab[tb + 15];
        if (labj_hi < 0) continue;  // all-bg col tile: skip MFMA too
        const bool slow = (labj_lo < 0) | ((labj_hi >= labi_lo) & (labj_lo <= labi_hi));
        const int jj = ct * 16 + m;
        f32x4 acc[4];
#pragma unroll
        for (int tr = 0; tr < 4; ++tr) acc[tr] = (f32x4){0.f, 0.f, 0.f, 0.f};
#pragma unroll
        for (int ks = 0; ks < 4; ++ks) {
          const int off = jj * 128 + ((ks * 4 + q) ^ m) * 8;  // swizzled chunk
          const bf16x8 bh = *(const bf16x8*)&Bh[cur][off];
#pragma unroll
          for (int tr = 0; tr < 4; ++tr)
            acc[tr] = __builtin_amdgcn_mfma_f32_16x16x32_bf16(Ah[tr][ks], bh, acc[tr], 0, 0, 0);
        }
        if (!slow) {
          // fast path (~97% of tiles): all-fg, no positives, no self
#pragma unroll
          for (int tr = 0; tr < 4; ++tr)
#pragma unroll
            for (int v = 0; v < 4; ++v)
              as_[tr][v] += __builtin_amdgcn_exp2f(acc[tr][v]);
        } else {
          const int labj = Lab[tb + m];
          const bool fgj = labj >= 0;
          const int jbase = cbase + ct * 16;
#pragma unroll
          for (int tr = 0; tr < 4; ++tr) {
            if (jbase == r0w + tr * 16) {  // wave-uniform diagonal-tile branch
#pragma unroll
              for (int v = 0; v < 4; ++v) {
                const float e = __builtin_amdgcn_exp2f(acc[tr][v]);
                const float em = (fgj && (m != q * 4 + v)) ? e : 0.0f;
                as_[tr][v] += em;
                ps[tr][v] += (labj == labi[tr][v]) ? em : 0.0f;
              }
            } else {
#pragma unroll
              for (int v = 0; v < 4; ++v) {
                const float e = __builtin_amdgcn_exp2f(acc[tr][v]);
                const float em = fgj ? e : 0.0f;
                as_[tr][v] += em;
                ps[tr][v] += (labj == labi[tr][v]) ? em : 0.0f;
              }
            }
          }
        }
      }
    }
  }
#undef STAGE

  // reduce across the 16 lanes (m) of each quad; plain float2 store per row
#pragma unroll
  for (int tr = 0; tr < 4; ++tr)
#pragma unroll
    for (int v = 0; v < 4; ++v) {
      float vp = ps[tr][v], va = as_[tr][v];
#pragma unroll
      for (int s = 1; s < 16; s <<= 1) {
        vp += __shfl_xor(vp, s);
        va += __shfl_xor(va, s);
      }
      if (m == 0)
        partials[(size_t)cc * N + r0w + tr * 16 + q * 4 + v] = make_float2(vp, va);
    }
}

// ---- kernel 3: combine partials -> per-row loss -> mean (self-finalizing) --
__global__ __launch_bounds__(256) void cpe_rows(const float2* __restrict__ partials,
                                                const int* __restrict__ slab,
                                                float* __restrict__ acc3,
                                                float* __restrict__ out) {
  const int r = blockIdx.x * 256 + threadIdx.x;
  float psr = 0.f, asr = 0.f;
#pragma unroll
  for (int c = 0; c < NCC; ++c) {
    const float2 p = partials[(size_t)c * N + r];
    psr += p.x;
    asr += p.y;
  }
  const bool fg = slab[r] >= 0;
  const bool valid = fg && (psr > 0.f);  // e>0 => (npos>0 <=> ps>0)
  const float loss = fminf(logf(asr / psr), 10.0f);
  float v0 = valid ? loss : 0.f;
  float v1 = valid ? 1.f : 0.f;
  float v2 = fg ? 1.f : 0.f;
#pragma unroll
  for (int s = 1; s < 64; s <<= 1) {
    v0 += __shfl_xor(v0, s);
    v1 += __shfl_xor(v1, s);
    v2 += __shfl_xor(v2, s);
  }
  __shared__ float red[3][4];
  const int w = threadIdx.x >> 6, l = threadIdx.x & 63;
  if (l == 0) { red[0][w] = v0; red[1][w] = v1; red[2][w] = v2; }
  __syncthreads();
  if (threadIdx.x == 0) {
    atomicAdd(&acc3[0], red[0][0] + red[0][1] + red[0][2] + red[0][3]);
    atomicAdd(&acc3[1], red[1][0] + red[1][1] + red[1][2] + red[1][3]);
    atomicAdd(&acc3[2], red[2][0] + red[2][1] + red[2][2] + red[2][3]);
    __threadfence();
    const unsigned old = atomicAdd((unsigned*)&acc3[3], 1u);
    if (old == gridDim.x - 1) {  // last block finalizes (device-scope reads)
      const float ls = atomicAdd(&acc3[0], 0.0f);
      const float nv = atomicAdd(&acc3[1], 0.0f);
      const float nf = atomicAdd(&acc3[2], 0.0f);
      out[0] = (nf >= 2.0f && nv > 0.0f) ? ls / fmaxf(nv, 1.0f) : 0.0f;
    }
  }
}

extern "C" void kernel_launch(void* const* d_in, const int* in_sizes, int n_in,
                              void* d_out, int out_size, void* d_ws, size_t ws_size,
                              hipStream_t stream) {
  const float* feat = (const float*)d_in[0];
  const int* labels = (const int*)d_in[1];
  float* out = (float*)d_out;
  char* ws = (char*)d_ws;
  u16* fhi = (u16*)ws;                                    // 2 MB
  float2* partials = (float2*)(ws + (size_t)N * D * 2);   // 1 MB (16 chunks)
  char* tail = ws + (size_t)N * D * 2 + (size_t)NCC * N * 8;
  int* slab = (int*)tail;                                 // 32 KB
  float* acc3 = (float*)(tail + N * 4);                   // 4 f32

  cpe_prep<<<PBLK, 256, 0, stream>>>(feat, labels, fhi, slab, acc3);
  cpe_main<<<dim3(N / RROWS, NCC), 512, 0, stream>>>(fhi, slab, partials);
  cpe_rows<<<N / 256, 256, 0, stream>>>(partials, slab, acc3, out);
}

// Round 15
// 102.228 us; speedup vs baseline: 1.6123x; 1.0686x over previous
//
#include <hip/hip_runtime.h>

#define N 8192
#define D 128
#define CHUNK 512
#define NCC (N / CHUNK)        // 16 column chunks
#define TILE_IT (CHUNK / 128)  // 4 B-tiles per chunk
#define RROWS 512              // rows per main block (8 waves)
#define NBIN 81                // labels -1..79 -> bins 0..80
#define PBLK 512               // prep grid (16 rows/block)

typedef unsigned short u16;
typedef __attribute__((ext_vector_type(8))) __bf16 bf16x8;
typedef __attribute__((ext_vector_type(4))) float f32x4;

// scale = sqrt(10 * log2(e)): dot of two scaled rows = log2(e^{cos/T}),
// so e^{sim} = exp2(acc) with NO per-element multiply.
#define PREP_SCALE 3.7982889979f

__device__ __forceinline__ u16 f2bf(float x) {
  unsigned u = __float_as_uint(x);
  u += 0x7fff + ((u >> 16) & 1);  // RNE
  return (u16)(u >> 16);
}

// ---- kernel 1: parallel counting-sort rank + normalize + bf16 write --------
// 512 blocks x 16 rows: each block independently histograms ALL labels
// (32 KB, L1-resident) + a partial histogram over j < myBase -> exact stable
// sorted position for its 16 rows. Redundant-but-parallel beats
// minimal-but-serial (R1: 1-block sort = 22us; R14: 64-block variant = +7us).
// Single-bf16 (no lo split): absmax 0.0 across R4-R14. Block 0 zeroes acc3.
__global__ __launch_bounds__(256) void cpe_prep(const float* __restrict__ feat,
                                                const int* __restrict__ labels,
                                                u16* __restrict__ fhi,
                                                int* __restrict__ slab,
                                                float* __restrict__ acc3) {
  __shared__ int hist[4][NBIN], part[4][NBIN], lbase[NBIN], lpos[16];
  const int tid = threadIdx.x;
  const int w = tid >> 6, l = tid & 63;
  const int bid = blockIdx.x;
  if (tid < NBIN) {
#pragma unroll
    for (int cp = 0; cp < 4; ++cp) { hist[cp][tid] = 0; part[cp][tid] = 0; }
  }
  if (bid == 0 && tid < 4) acc3[tid] = 0.0f;
  __syncthreads();
  const int myBase = bid * 16;
  for (int j = tid; j < N; j += 256) {
    const int lab = labels[j] + 1;
    atomicAdd(&hist[w][lab], 1);
    if (j < myBase) atomicAdd(&part[w][lab], 1);
  }
  __syncthreads();
  if (tid < NBIN) {
    hist[0][tid] += hist[1][tid] + hist[2][tid] + hist[3][tid];
    part[0][tid] += part[1][tid] + part[2][tid] + part[3][tid];
  }
  __syncthreads();
  if (tid == 0) {
    int s = 0;
    for (int b = 0; b < NBIN; ++b) { lbase[b] = s; s += hist[0][b]; }
  }
  __syncthreads();
  if (tid < 16) {
    const int L = labels[myBase + tid] + 1;
    int pos = lbase[L] + part[0][L];
    for (int k = 0; k < tid; ++k) pos += (labels[myBase + k] + 1 == L) ? 1 : 0;
    lpos[tid] = pos;
    slab[pos] = L - 1;
  }
  __syncthreads();
#pragma unroll
  for (int rr = 0; rr < 4; ++rr) {
    const int k = w * 4 + rr;
    const float2 x = *(const float2*)&feat[(myBase + k) * D + l * 2];
    float s = x.x * x.x + x.y * x.y;
#pragma unroll
    for (int sh = 1; sh < 64; sh <<= 1) s += __shfl_xor(s, sh);
    const float inv = PREP_SCALE / fmaxf(sqrtf(s), 1e-12f);
    const int pos = lpos[k];
    *(ushort2*)&fhi[pos * D + l * 2] = make_ushort2(f2bf(x.x * inv), f2bf(x.y * inv));
  }
}

// ---- kernel 2: fused sim + masked reductions (session best: 102.16us) ------
// 512-row blocks (512 thr, 8 waves), grid 16x16 = 256 blocks = 1/CU; B-tile
// shared by 8 waves. 2-phase LDS staging (global_load_lds 16B + XOR-swizzled
// dest via pre-swizzled global src), counted vmcnt (T4 — never drain to 0
// mid-loop), raw s_barrier + sched_barrier fences (m214 rule 18).
// SORTED label order: ~97% of 16-col tiles take the {exp2, add} fast path;
// all-bg tiles skip MFMA entirely. loss = log(as/ps): the mxe term and all
// clips are provably inactive (|sim|<=10 bounded by cosine; absmax 0.0
// across R3-R14). No launch_bounds reg-cap (R4: (,4) = spill storm).
__global__ __launch_bounds__(512) void cpe_main(
    const u16* __restrict__ fhi, const int* __restrict__ slab,
    float2* __restrict__ partials) {
  __shared__ __align__(16) u16 Bh[2][128 * 128];  // 2 x 32 KB, XOR-swizzled
  __shared__ int Lab[CHUNK];                      // 2 KB
  const int rt = blockIdx.x, cc = blockIdx.y;     // grid (16,16)
  const int tid = threadIdx.x;
  const int w = tid >> 6, l = tid & 63, q = l >> 4, m = l & 15;
  const int r0w = rt * RROWS + w * 64;
  const int cbase0 = cc * CHUNK;

  // stage a 128-col tile (32 KB): 512 thr x 16B x 4 rounds. LDS slot
  // p = w*256 + n*64 + lane -> (r = p>>4, c' = p&15 = m); c = c' ^ (r&15).
#define STAGE(buf, itv)                                                        \
  do {                                                                         \
    const int cbase_ = cbase0 + (itv) * 128;                                   \
    _Pragma("unroll") for (int n = 0; n < 4; ++n) {                            \
      const int r_ = w * 16 + n * 4 + q;                                       \
      const int c_ = m ^ (r_ & 15);                                            \
      const u16* gh_ = &fhi[(size_t)(cbase_ + r_) * D + c_ * 8];               \
      __builtin_amdgcn_global_load_lds(                                        \
          (const __attribute__((address_space(1))) unsigned*)gh_,              \
          (__attribute__((address_space(3))) unsigned*)&Bh[buf][(w * 256 + n * 64) * 8], \
          16, 0, 0);                                                           \
    }                                                                          \
  } while (0)

  Lab[tid] = slab[cbase0 + tid];  // 512 threads cover CHUNK=512

  // wave-uniform row-label range (labels sorted ascending)
  const int labi_lo = slab[r0w], labi_hi = slab[r0w + 63];

  // A fragments + row labels straight from global (L2-resident, once).
  // Issued BEFORE the stages so compiler A-waits never drain stage loads.
  bf16x8 Ah[4][4];
  int labi[4][4];
#pragma unroll
  for (int tr = 0; tr < 4; ++tr) {
    const int row = r0w + tr * 16 + m;
#pragma unroll
    for (int ks = 0; ks < 4; ++ks)
      Ah[tr][ks] = *(const bf16x8*)&fhi[row * D + ks * 32 + q * 8];
#pragma unroll
    for (int v = 0; v < 4; ++v) labi[tr][v] = slab[r0w + tr * 16 + q * 4 + v];
  }

  float ps[4][4], as_[4][4];
#pragma unroll
  for (int tr = 0; tr < 4; ++tr)
#pragma unroll
    for (int v = 0; v < 4; ++v) { ps[tr][v] = 0.f; as_[tr][v] = 0.f; }

  __builtin_amdgcn_sched_barrier(0);  // pin: A/Lab loads above, stages below
  STAGE(0, 0);                        // tile 0 in flight (NOT drained)

  // Lab ds_writes visible to all waves; stages stay outstanding (no vmcnt).
  asm volatile("s_waitcnt lgkmcnt(0)" ::: "memory");
  __builtin_amdgcn_s_barrier();
  __builtin_amdgcn_sched_barrier(0);

#pragma unroll
  for (int it = 0; it < TILE_IT; ++it) {
    const int cur = it & 1;
    if (it > 0) {
      // (A) all waves done reading Bh[cur] from iteration it-1 — safe to
      // overwrite it with tile it+1. No vmcnt drain here.
      asm volatile("s_waitcnt lgkmcnt(0)" ::: "memory");
      __builtin_amdgcn_s_barrier();
      __builtin_amdgcn_sched_barrier(0);
    }
    if (it + 1 < TILE_IT) STAGE(cur ^ 1, it + 1);
    // (B) tile `cur` landed: counted wait leaves the 4 just-issued next-tile
    // loads in flight (T4 — never drain to 0 mid-loop).
    if (it + 1 < TILE_IT)
      asm volatile("s_waitcnt vmcnt(4)" ::: "memory");
    else
      asm volatile("s_waitcnt vmcnt(0)" ::: "memory");
    __builtin_amdgcn_s_barrier();
    __builtin_amdgcn_sched_barrier(0);

    const int cbase = cbase0 + it * 128;
    for (int ct = 0; ct < 8; ++ct) {
      const int tb = it * 128 + ct * 16;
      const int labj_lo = Lab[tb], labj_hi = Lab[tb + 15];
      if (labj_hi < 0) continue;  // all-bg tile: every em==0, skip MFMA too
      const bool slow = (labj_lo < 0) | ((labj_hi >= labi_lo) & (labj_lo <= labi_hi));
      const int jj = ct * 16 + m;
      f32x4 acc[4];
#pragma unroll
      for (int tr = 0; tr < 4; ++tr) acc[tr] = (f32x4){0.f, 0.f, 0.f, 0.f};
#pragma unroll
      for (int ks = 0; ks < 4; ++ks) {
        const int off = jj * 128 + ((ks * 4 + q) ^ m) * 8;  // swizzled chunk
        const bf16x8 bh = *(const bf16x8*)&Bh[cur][off];
#pragma unroll
        for (int tr = 0; tr < 4; ++tr)
          acc[tr] = __builtin_amdgcn_mfma_f32_16x16x32_bf16(Ah[tr][ks], bh, acc[tr], 0, 0, 0);
      }
      if (!slow) {
        // fast path (~97% of tiles): all-fg, no positives, no self
#pragma unroll
        for (int tr = 0; tr < 4; ++tr)
#pragma unroll
          for (int v = 0; v < 4; ++v)
            as_[tr][v] += __builtin_amdgcn_exp2f(acc[tr][v]);
      } else {
        const int labj = Lab[tb + m];
        const bool fgj = labj >= 0;
        const int jbase = cbase + ct * 16;
#pragma unroll
        for (int tr = 0; tr < 4; ++tr) {
          if (jbase == r0w + tr * 16) {  // wave-uniform diagonal-tile branch
#pragma unroll
            for (int v = 0; v < 4; ++v) {
              const float e = __builtin_amdgcn_exp2f(acc[tr][v]);
              const float em = (fgj && (m != q * 4 + v)) ? e : 0.0f;
              as_[tr][v] += em;
              ps[tr][v] += (labj == labi[tr][v]) ? em : 0.0f;
            }
          } else {
#pragma unroll
            for (int v = 0; v < 4; ++v) {
              const float e = __builtin_amdgcn_exp2f(acc[tr][v]);
              const float em = fgj ? e : 0.0f;
              as_[tr][v] += em;
              ps[tr][v] += (labj == labi[tr][v]) ? em : 0.0f;
            }
          }
        }
      }
    }
  }
#undef STAGE

  // reduce across the 16 lanes (m) of each quad; plain float2 store per row
#pragma unroll
  for (int tr = 0; tr < 4; ++tr)
#pragma unroll
    for (int v = 0; v < 4; ++v) {
      float vp = ps[tr][v], va = as_[tr][v];
#pragma unroll
      for (int s = 1; s < 16; s <<= 1) {
        vp += __shfl_xor(vp, s);
        va += __shfl_xor(va, s);
      }
      if (m == 0)
        partials[(size_t)cc * N + r0w + tr * 16 + q * 4 + v] = make_float2(vp, va);
    }
}

// ---- kernel 3: combine partials -> per-row loss -> mean (self-finalizing) --
// Cross-dispatch visibility of partials is free (kernel-boundary
// release/acquire) — no fences needed (R5/R13: in-kernel grid sync costs
// tens of us at grid scale on gfx950).
__global__ __launch_bounds__(256) void cpe_rows(const float2* __restrict__ partials,
                                                const int* __restrict__ slab,
                                                float* __restrict__ acc3,
                                                float* __restrict__ out) {
  const int r = blockIdx.x * 256 + threadIdx.x;
  float psr = 0.f, asr = 0.f;
#pragma unroll
  for (int c = 0; c < NCC; ++c) {
    const float2 p = partials[(size_t)c * N + r];
    psr += p.x;
    asr += p.y;
  }
  const bool fg = slab[r] >= 0;
  const bool valid = fg && (psr > 0.f);  // e>0 => (npos>0 <=> ps>0)
  const float loss = fminf(logf(asr / psr), 10.0f);
  float v0 = valid ? loss : 0.f;
  float v1 = valid ? 1.f : 0.f;
  float v2 = fg ? 1.f : 0.f;
#pragma unroll
  for (int s = 1; s < 64; s <<= 1) {
    v0 += __shfl_xor(v0, s);
    v1 += __shfl_xor(v1, s);
    v2 += __shfl_xor(v2, s);
  }
  __shared__ float red[3][4];
  const int w = threadIdx.x >> 6, l = threadIdx.x & 63;
  if (l == 0) { red[0][w] = v0; red[1][w] = v1; red[2][w] = v2; }
  __syncthreads();
  if (threadIdx.x == 0) {
    atomicAdd(&acc3[0], red[0][0] + red[0][1] + red[0][2] + red[0][3]);
    atomicAdd(&acc3[1], red[1][0] + red[1][1] + red[1][2] + red[1][3]);
    atomicAdd(&acc3[2], red[2][0] + red[2][1] + red[2][2] + red[2][3]);
    __threadfence();
    const unsigned old = atomicAdd((unsigned*)&acc3[3], 1u);
    if (old == gridDim.x - 1) {  // last block finalizes (device-scope reads)
      const float ls = atomicAdd(&acc3[0], 0.0f);
      const float nv = atomicAdd(&acc3[1], 0.0f);
      const float nf = atomicAdd(&acc3[2], 0.0f);
      out[0] = (nf >= 2.0f && nv > 0.0f) ? ls / fmaxf(nv, 1.0f) : 0.0f;
    }
  }
}

extern "C" void kernel_launch(void* const* d_in, const int* in_sizes, int n_in,
                              void* d_out, int out_size, void* d_ws, size_t ws_size,
                              hipStream_t stream) {
  const float* feat = (const float*)d_in[0];
  const int* labels = (const int*)d_in[1];
  float* out = (float*)d_out;
  char* ws = (char*)d_ws;
  u16* fhi = (u16*)ws;                                    // 2 MB
  float2* partials = (float2*)(ws + (size_t)N * D * 2);   // 1 MB (16 chunks)
  char* tail = ws + (size_t)N * D * 2 + (size_t)NCC * N * 8;
  int* slab = (int*)tail;                                 // 32 KB
  float* acc3 = (float*)(tail + N * 4);                   // 4 f32

  cpe_prep<<<PBLK, 256, 0, stream>>>(feat, labels, fhi, slab, acc3);
  cpe_main<<<dim3(N / RROWS, NCC), 512, 0, stream>>>(fhi, slab, partials);
  cpe_rows<<<N / 256, 256, 0, stream>>>(partials, slab, acc3, out);
}